// Round 7
// baseline (235.710 us; speedup 1.0000x reference)
//
#include <hip/hip_runtime.h>
#include <math.h>

#define LSEQ  512
#define BT    128
#define INF   512
#define HH    60
#define NSTEP 1536   // 3*LSEQ
#define CHUNK 24     // steps per lane in scan kernel: 1536 / 64

#define MTILE 128    // rows per block (k_phi)
#define KTILE 64     // K staged per LDS tile
#define NTILES (INF / KTILE)   // 8
#define APAD  72     // bf16 row stride for A tiles: rows m,m+8 alias -> 2-way (free)

typedef __attribute__((ext_vector_type(8))) short bf16x8;
typedef __attribute__((ext_vector_type(4))) float floatx4;

// ---------- bf16 split helpers ---------------------------------------------
__device__ __forceinline__ unsigned short bf16_rn(float x) {
  unsigned u = __float_as_uint(x);
  return (unsigned short)((u + 0x7FFFu + ((u >> 16) & 1u)) >> 16);
}
__device__ __forceinline__ void split2(float x, unsigned short& h, unsigned short& l) {
  h = bf16_rn(x);
  float hf = __uint_as_float(((unsigned)h) << 16);
  l = bf16_rn(x - hf);
}

// ---------- W pre-conversion: fp32 -> (Wh, Wl) bf16 [64][512] --------------
__global__ __launch_bounds__(256) void k_wconv(
    const float* __restrict__ W, unsigned short* __restrict__ Wh,
    unsigned short* __restrict__ Wl) {
  const int idx = blockIdx.x * 256 + threadIdx.x;   // 0 .. 32767
  const int h = idx >> 9, k = idx & 511;
  float x = (h < HH) ? W[h * INF + k] : 0.f;
  unsigned short hb, lb; split2(x, hb, lb);
  Wh[idx] = hb; Wl[idx] = lb;
}

// ---------- kernel 1: split-bf16 MFMA GEMM + softmax + torsion angles ------
// Block: 256 thr = 4 waves, 128 rows x 64 cols (60 used). Wave w: rows
// [32w,32w+32) as 2 m-tiles x 4 n-tiles of mfma_f32_16x16x32_bf16.
// acc += Ah*Bh + Ah*Bl + Al*Bh  (split-fp32, ~2^-18 relative).
// Register-prefetch pipeline: next A-tile loaded into VGPRs during current
// tile's MFMA phase (reg loads don't force vmcnt(0) at s_barrier).
__global__ __launch_bounds__(256, 3) void k_phi(
    const float* __restrict__ inp, const unsigned short* __restrict__ Wh,
    const unsigned short* __restrict__ Wl, const float* __restrict__ bias,
    const float* __restrict__ alphabet, float* __restrict__ phi_out) {
  __shared__ unsigned short Ah[MTILE * APAD];   // 18432 B
  __shared__ unsigned short Al[MTILE * APAD];   // 18432 B
  __shared__ float sS[HH * 3], sC[HH * 3], sBias[64];

  const int tid  = threadIdx.x;
  const int lane = tid & 63;
  const int wid  = tid >> 6;
  const int c    = lane & 15;        // col-within-tile / frag row index
  const int quad = lane >> 4;        // 0..3
  const int row0 = blockIdx.x * MTILE;

  if (tid < HH * 3) { float a = alphabet[tid]; sS[tid] = __sinf(a); sC[tid] = __cosf(a); }
  if (tid >= 192 && tid < 256) { int n = tid - 192; sBias[n] = (n < HH) ? bias[n] : 0.f; }

  floatx4 acc[2][4];
#pragma unroll
  for (int mt = 0; mt < 2; ++mt)
#pragma unroll
    for (int nt = 0; nt < 4; ++nt) acc[mt][nt] = (floatx4){0.f, 0.f, 0.f, 0.f};

  // per-thread staging coordinates (constant across tiles)
  // f4i = i*256 + tid ; r = f4i>>4 (row 0..127), c4 = f4i&15 (float4 chunk)
  const float* gbase = inp + (size_t)row0 * INF;

  float4 pre[8];
#pragma unroll
  for (int i = 0; i < 8; ++i) {
    const int f4i = i * 256 + tid;
    const int r = f4i >> 4, c4 = f4i & 15;
    pre[i] = *(const float4*)(gbase + (size_t)r * INF + 4 * c4);
  }

  for (int t = 0; t < NTILES; ++t) {
    const int k0 = t * KTILE;
    if (t) __syncthreads();            // previous compute done -> safe to overwrite
    // ---- convert prefetched regs -> bf16 h/l in LDS ----
#pragma unroll
    for (int i = 0; i < 8; ++i) {
      const int f4i = i * 256 + tid;
      const int r = f4i >> 4, c4 = f4i & 15;
      float4 v = pre[i];
      unsigned short h0,l0,h1,l1,h2,l2,h3,l3;
      split2(v.x, h0, l0); split2(v.y, h1, l1);
      split2(v.z, h2, l2); split2(v.w, h3, l3);
      uint2 ph = make_uint2((unsigned)h0 | ((unsigned)h1 << 16),
                            (unsigned)h2 | ((unsigned)h3 << 16));
      uint2 pl = make_uint2((unsigned)l0 | ((unsigned)l1 << 16),
                            (unsigned)l2 | ((unsigned)l3 << 16));
      *(uint2*)&Ah[r * APAD + 4 * c4] = ph;
      *(uint2*)&Al[r * APAD + 4 * c4] = pl;
    }
    __syncthreads();

    // ---- issue next tile's global loads (in flight during MFMA phase) ----
    if (t + 1 < NTILES) {
#pragma unroll
      for (int i = 0; i < 8; ++i) {
        const int f4i = i * 256 + tid;
        const int r = f4i >> 4, c4 = f4i & 15;
        pre[i] = *(const float4*)(gbase + (size_t)r * INF + k0 + KTILE + 4 * c4);
      }
    }

#pragma unroll
    for (int ks = 0; ks < 2; ++ks) {
      const int kl = ks * 32;                 // k within tile
      const int kg = k0 + kl;                 // global k
      // B fragments from global (L1/L2-hot, 128 KB total)
      bf16x8 Bh[4], Bl[4];
#pragma unroll
      for (int nt = 0; nt < 4; ++nt) {
        const int h = nt * 16 + c;
        Bh[nt] = *(const bf16x8*)(Wh + (size_t)h * INF + kg + quad * 8);
        Bl[nt] = *(const bf16x8*)(Wl + (size_t)h * INF + kg + quad * 8);
      }
      // A fragments from LDS
      bf16x8 Af[2], Alf[2];
#pragma unroll
      for (int mt = 0; mt < 2; ++mt) {
        const int m = wid * 32 + mt * 16 + c;
        Af[mt]  = *(const bf16x8*)(&Ah[m * APAD + kl + quad * 8]);
        Alf[mt] = *(const bf16x8*)(&Al[m * APAD + kl + quad * 8]);
      }
#pragma unroll
      for (int mt = 0; mt < 2; ++mt)
#pragma unroll
        for (int nt = 0; nt < 4; ++nt) {
          acc[mt][nt] = __builtin_amdgcn_mfma_f32_16x16x32_bf16(Af[mt],  Bh[nt], acc[mt][nt], 0, 0, 0);
          acc[mt][nt] = __builtin_amdgcn_mfma_f32_16x16x32_bf16(Af[mt],  Bl[nt], acc[mt][nt], 0, 0, 0);
          acc[mt][nt] = __builtin_amdgcn_mfma_f32_16x16x32_bf16(Alf[mt], Bh[nt], acc[mt][nt], 0, 0, 0);
        }
    }
    __syncthreads();
  }

  // ---- epilogue: C/D layout row = quad*4+reg, col = lane&15 ----
#pragma unroll
  for (int mt = 0; mt < 2; ++mt) {
#pragma unroll
    for (int reg = 0; reg < 4; ++reg) {
      float lg[4];  bool val[4];
#pragma unroll
      for (int nt = 0; nt < 4; ++nt) {
        const int n = nt * 16 + c;
        val[nt] = (n < HH);
        lg[nt] = acc[mt][nt][reg] + sBias[n];
      }
      float m = -1e30f;
#pragma unroll
      for (int nt = 0; nt < 4; ++nt) if (val[nt]) m = fmaxf(m, lg[nt]);
#pragma unroll
      for (int d = 1; d < 16; d <<= 1) m = fmaxf(m, __shfl_xor(m, d, 64));

      float s0=0.f,c0=0.f,s1=0.f,c1=0.f,s2=0.f,c2=0.f;
#pragma unroll
      for (int nt = 0; nt < 4; ++nt) {
        const int n = nt * 16 + c;
        float e = val[nt] ? __expf(lg[nt] - m) : 0.f;
        s0 = fmaf(e, sS[n*3+0], s0);  c0 = fmaf(e, sC[n*3+0], c0);
        s1 = fmaf(e, sS[n*3+1], s1);  c1 = fmaf(e, sC[n*3+1], c1);
        s2 = fmaf(e, sS[n*3+2], s2);  c2 = fmaf(e, sC[n*3+2], c2);
      }
#pragma unroll
      for (int d = 1; d < 16; d <<= 1) {
        s0 += __shfl_xor(s0, d, 64);  c0 += __shfl_xor(c0, d, 64);
        s1 += __shfl_xor(s1, d, 64);  c1 += __shfl_xor(c1, d, 64);
        s2 += __shfl_xor(s2, d, 64);  c2 += __shfl_xor(c2, d, 64);
      }
      if (c == 0) {
        const int row = row0 + wid * 32 + mt * 16 + quad * 4 + reg;
        const int l  = row >> 7;        // / BT
        const int bb = row & 127;       // % BT
        float* pp = phi_out + (size_t)bb * NSTEP + 3 * l;
        pp[0] = atan2f(s0, c0);
        pp[1] = atan2f(s1, c1);
        pp[2] = atan2f(s2, c2);
      }
    }
  }
}

// ---------- rigid transform (3x3 rotation row-major + translation) ----------
struct Xf { float r[9]; float p[3]; };

__device__ __forceinline__ Xf compose(const Xf& A, const Xf& B) {
  Xf o;
#pragma unroll
  for (int i = 0; i < 3; ++i) {
#pragma unroll
    for (int j = 0; j < 3; ++j) {
      o.r[i*3+j] = fmaf(A.r[i*3+0], B.r[0+j],
                   fmaf(A.r[i*3+1], B.r[3+j],
                        A.r[i*3+2] * B.r[6+j]));
    }
    o.p[i] = fmaf(A.r[i*3+0], B.p[0],
             fmaf(A.r[i*3+1], B.p[1],
             fmaf(A.r[i*3+2], B.p[2], A.p[i])));
  }
  return o;
}

__device__ __forceinline__ Xf make_T(float phi, float st, float ct, float r) {
  float sp = __sinf(phi), cp = __cosf(phi);
  Xf T;
  T.r[0] = ct;      T.r[1] = -st;     T.r[2] = 0.f;
  T.r[3] = cp * st; T.r[4] = ct * cp; T.r[5] = -sp;
  T.r[6] = sp * st; T.r[7] = ct * sp; T.r[8] = cp;
  T.p[0] = r * ct;  T.p[1] = r * T.r[3]; T.p[2] = r * T.r[6];
  return T;
}

__device__ __forceinline__ void set_identity(Xf& X) {
  X.r[0]=1.f; X.r[1]=0.f; X.r[2]=0.f;
  X.r[3]=0.f; X.r[4]=1.f; X.r[5]=0.f;
  X.r[6]=0.f; X.r[7]=0.f; X.r[8]=1.f;
  X.p[0]=0.f; X.p[1]=0.f; X.p[2]=0.f;
}

// ---------- kernel 2: parallel rigid-transform scan ------------------------
__global__ __launch_bounds__(64) void k_scan(
    const float* __restrict__ phi, const float* __restrict__ bl,
    const float* __restrict__ ba, float* __restrict__ out) {
  const int b = blockIdx.x;       // chain 0..127
  const int t = threadIdx.x;      // lane 0..63

  float st[3], ct[3], rr[3];
#pragma unroll
  for (int j = 0; j < 3; ++j) {
    float a = ba[j];
    st[j] = __sinf(a); ct[j] = __cosf(a); rr[j] = bl[j];
  }

  float f[CHUNK];
  const float4* ph4 = (const float4*)(phi + (size_t)b * NSTEP + t * CHUNK);
#pragma unroll
  for (int q = 0; q < CHUNK/4; ++q) {
    float4 v = ph4[q];
    f[4*q+0] = v.x; f[4*q+1] = v.y; f[4*q+2] = v.z; f[4*q+3] = v.w;
  }

  Xf Q = make_T(f[0], st[0], ct[0], rr[0]);
#pragma unroll
  for (int s = 1; s < CHUNK; ++s)
    Q = compose(Q, make_T(f[s], st[s%3], ct[s%3], rr[s%3]));

#pragma unroll
  for (int d = 1; d < 64; d <<= 1) {
    Xf O;
#pragma unroll
    for (int q = 0; q < 9; ++q) O.r[q] = __shfl_up(Q.r[q], d, 64);
#pragma unroll
    for (int q = 0; q < 3; ++q) O.p[q] = __shfl_up(Q.p[q], d, 64);
    if (t < d) set_identity(O);
    Q = compose(O, Q);
  }

  Xf E;
#pragma unroll
  for (int q = 0; q < 9; ++q) E.r[q] = __shfl_up(Q.r[q], 1, 64);
#pragma unroll
  for (int q = 0; q < 3; ++q) E.p[q] = __shfl_up(Q.p[q], 1, 64);
  if (t == 0) set_identity(E);

  Xf S0;
  S0.r[0] = 0.f;                  S0.r[1] = 0.816496580927726f;   S0.r[2] = 0.5773502691896258f;
  S0.r[3] = -0.7071067811865475f; S0.r[4] = -0.4082482904638631f; S0.r[5] = 0.5773502691896258f;
  S0.r[6] = 0.7071067811865475f;  S0.r[7] = -0.4082482904638631f; S0.r[8] = 0.5773502691896258f;
  S0.p[0] = 0.f; S0.p[1] = 0.f; S0.p[2] = 1.f;

  Xf cur = compose(S0, E);

  float* op = out + (size_t)(t * CHUNK) * (BT * 3) + b * 3;
#pragma unroll
  for (int s = 0; s < CHUNK; ++s) {
    cur = compose(cur, make_T(f[s], st[s%3], ct[s%3], rr[s%3]));
    op[(size_t)s * (BT*3) + 0] = cur.p[0];
    op[(size_t)s * (BT*3) + 1] = cur.p[1];
    op[(size_t)s * (BT*3) + 2] = cur.p[2];
  }
}

// ---------- launch ---------------------------------------------------------
extern "C" void kernel_launch(void* const* d_in, const int* in_sizes, int n_in,
                              void* d_out, int out_size, void* d_ws, size_t ws_size,
                              hipStream_t stream) {
  const float* inp      = (const float*)d_in[0];
  const float* W        = (const float*)d_in[1];
  const float* bias     = (const float*)d_in[2];
  const float* alphabet = (const float*)d_in[3];
  const float* bl       = (const float*)d_in[4];
  const float* ba       = (const float*)d_in[5];
  float* out = (float*)d_out;

  float* phi = (float*)d_ws;                                    // 786432 B
  unsigned short* Wh = (unsigned short*)((char*)d_ws + 786432); // 65536 B
  unsigned short* Wl = Wh + 64 * INF;                           // 65536 B

  k_wconv<<<dim3(128), dim3(256), 0, stream>>>(W, Wh, Wl);
  k_phi<<<dim3((LSEQ*BT)/MTILE), dim3(256), 0, stream>>>(inp, Wh, Wl, bias, alphabet, phi);
  k_scan<<<dim3(BT), dim3(64), 0, stream>>>(phi, bl, ba, out);
}

// Round 8
// 234.044 us; speedup vs baseline: 1.0071x; 1.0071x over previous
//
#include <hip/hip_runtime.h>
#include <math.h>

#define LSEQ  512
#define BT    128
#define INF   512
#define HH    60
#define NSTEP 1536   // 3*LSEQ
#define CHUNK 24     // steps per lane in scan kernel: 1536 / 64

#define MTILE 128    // rows per block (k_phi); wave owns 32 rows

typedef __attribute__((ext_vector_type(8))) short bf16x8;
typedef __attribute__((ext_vector_type(4))) float floatx4;

// ---------- bf16 split helpers ---------------------------------------------
__device__ __forceinline__ unsigned short bf16_rn(float x) {
  unsigned u = __float_as_uint(x);
  return (unsigned short)((u + 0x7FFFu + ((u >> 16) & 1u)) >> 16);
}
__device__ __forceinline__ void split2(float x, unsigned short& h, unsigned short& l) {
  h = bf16_rn(x);
  float hf = __uint_as_float(((unsigned)h) << 16);
  l = bf16_rn(x - hf);
}

// ---------- W pre-conversion: fp32 -> (Wh, Wl) bf16 [64][512] --------------
__global__ __launch_bounds__(256) void k_wconv(
    const float* __restrict__ W, unsigned short* __restrict__ Wh,
    unsigned short* __restrict__ Wl) {
  const int idx = blockIdx.x * 256 + threadIdx.x;   // 0 .. 32767
  const int h = idx >> 9, k = idx & 511;
  float x = (h < HH) ? W[h * INF + k] : 0.f;
  unsigned short hb, lb; split2(x, hb, lb);
  Wh[idx] = hb; Wl[idx] = lb;
}

// ---------- kernel 1: split-bf16 MFMA GEMM + softmax + torsion angles ------
// Barrier-free K-loop: A fragments loaded straight from global (each row is
// owned by exactly one wave -> no reuse lost), split to bf16 h/l in registers.
// B fragments from L1/L2-hot Wh/Wl. acc += Ah*Bh + Ah*Bl + Al*Bh.
// No LDS, no __syncthreads in the K-loop -> waves pipeline independently.
__global__ __launch_bounds__(256, 2) void k_phi(
    const float* __restrict__ inp, const unsigned short* __restrict__ Wh,
    const unsigned short* __restrict__ Wl, const float* __restrict__ bias,
    const float* __restrict__ alphabet, float* __restrict__ phi_out) {
  __shared__ float sS[HH * 3], sC[HH * 3], sBias[64];

  const int tid  = threadIdx.x;
  const int lane = tid & 63;
  const int wid  = tid >> 6;
  const int c    = lane & 15;        // frag row/col index
  const int quad = lane >> 4;        // 0..3
  const int row0 = blockIdx.x * MTILE;

  if (tid < HH * 3) { float a = alphabet[tid]; sS[tid] = __sinf(a); sC[tid] = __cosf(a); }
  if (tid >= 192 && tid < 256) { int n = tid - 192; sBias[n] = (n < HH) ? bias[n] : 0.f; }

  floatx4 acc[2][4];
#pragma unroll
  for (int mt = 0; mt < 2; ++mt)
#pragma unroll
    for (int nt = 0; nt < 4; ++nt) acc[mt][nt] = (floatx4){0.f, 0.f, 0.f, 0.f};

  // per-lane A row bases: wave w owns rows [32w, 32w+32); m-tile mt row = 16mt + c
  const float* a0p = inp + (size_t)(row0 + wid * 32 + c)      * INF + quad * 8;
  const float* a1p = inp + (size_t)(row0 + wid * 32 + 16 + c) * INF + quad * 8;
  const unsigned short* whp = Wh + (size_t)c * INF + quad * 8;
  const unsigned short* wlp = Wl + (size_t)c * INF + quad * 8;

#pragma unroll 2
  for (int ks = 0; ks < INF / 32; ++ks) {
    const int kg = ks * 32;
    // ---- A: 8 fp32 per m-tile straight from global ----
    float4 a00 = *(const float4*)(a0p + kg);
    float4 a01 = *(const float4*)(a0p + kg + 4);
    float4 a10 = *(const float4*)(a1p + kg);
    float4 a11 = *(const float4*)(a1p + kg + 4);
    // ---- B: 4 n-tiles x (h,l) from global (L1/L2-hot) ----
    bf16x8 Bh[4], Bl[4];
#pragma unroll
    for (int nt = 0; nt < 4; ++nt) {
      Bh[nt] = *(const bf16x8*)(whp + (size_t)(nt * 16) * INF + kg);
      Bl[nt] = *(const bf16x8*)(wlp + (size_t)(nt * 16) * INF + kg);
    }
    // ---- split A to bf16 h/l fragments in registers ----
    bf16x8 Ah[2], Al[2];
    {
      float av[2][8] = {{a00.x,a00.y,a00.z,a00.w,a01.x,a01.y,a01.z,a01.w},
                        {a10.x,a10.y,a10.z,a10.w,a11.x,a11.y,a11.z,a11.w}};
#pragma unroll
      for (int mt = 0; mt < 2; ++mt)
#pragma unroll
        for (int j = 0; j < 8; ++j) {
          unsigned short hb, lb; split2(av[mt][j], hb, lb);
          Ah[mt][j] = (short)hb; Al[mt][j] = (short)lb;
        }
    }
#pragma unroll
    for (int mt = 0; mt < 2; ++mt)
#pragma unroll
      for (int nt = 0; nt < 4; ++nt) {
        acc[mt][nt] = __builtin_amdgcn_mfma_f32_16x16x32_bf16(Ah[mt], Bh[nt], acc[mt][nt], 0, 0, 0);
        acc[mt][nt] = __builtin_amdgcn_mfma_f32_16x16x32_bf16(Ah[mt], Bl[nt], acc[mt][nt], 0, 0, 0);
        acc[mt][nt] = __builtin_amdgcn_mfma_f32_16x16x32_bf16(Al[mt], Bh[nt], acc[mt][nt], 0, 0, 0);
      }
  }

  __syncthreads();   // sS/sC/sBias visible

  // ---- epilogue: C/D layout row = quad*4+reg, col = lane&15 ----
#pragma unroll
  for (int mt = 0; mt < 2; ++mt) {
#pragma unroll
    for (int reg = 0; reg < 4; ++reg) {
      float lg[4];  bool val[4];
#pragma unroll
      for (int nt = 0; nt < 4; ++nt) {
        const int n = nt * 16 + c;
        val[nt] = (n < HH);
        lg[nt] = acc[mt][nt][reg] + sBias[n];
      }
      float m = -1e30f;
#pragma unroll
      for (int nt = 0; nt < 4; ++nt) if (val[nt]) m = fmaxf(m, lg[nt]);
#pragma unroll
      for (int d = 1; d < 16; d <<= 1) m = fmaxf(m, __shfl_xor(m, d, 64));

      float s0=0.f,c0=0.f,s1=0.f,c1=0.f,s2=0.f,c2=0.f;
#pragma unroll
      for (int nt = 0; nt < 4; ++nt) {
        const int n = nt * 16 + c;
        float e = val[nt] ? __expf(lg[nt] - m) : 0.f;
        s0 = fmaf(e, sS[n*3+0], s0);  c0 = fmaf(e, sC[n*3+0], c0);
        s1 = fmaf(e, sS[n*3+1], s1);  c1 = fmaf(e, sC[n*3+1], c1);
        s2 = fmaf(e, sS[n*3+2], s2);  c2 = fmaf(e, sC[n*3+2], c2);
      }
#pragma unroll
      for (int d = 1; d < 16; d <<= 1) {
        s0 += __shfl_xor(s0, d, 64);  c0 += __shfl_xor(c0, d, 64);
        s1 += __shfl_xor(s1, d, 64);  c1 += __shfl_xor(c1, d, 64);
        s2 += __shfl_xor(s2, d, 64);  c2 += __shfl_xor(c2, d, 64);
      }
      if (c == 0) {
        const int row = row0 + wid * 32 + mt * 16 + quad * 4 + reg;
        const int l  = row >> 7;        // / BT
        const int bb = row & 127;       // % BT
        float* pp = phi_out + (size_t)bb * NSTEP + 3 * l;
        pp[0] = atan2f(s0, c0);
        pp[1] = atan2f(s1, c1);
        pp[2] = atan2f(s2, c2);
      }
    }
  }
}

// ---------- rigid transform (3x3 rotation row-major + translation) ----------
struct Xf { float r[9]; float p[3]; };

__device__ __forceinline__ Xf compose(const Xf& A, const Xf& B) {
  Xf o;
#pragma unroll
  for (int i = 0; i < 3; ++i) {
#pragma unroll
    for (int j = 0; j < 3; ++j) {
      o.r[i*3+j] = fmaf(A.r[i*3+0], B.r[0+j],
                   fmaf(A.r[i*3+1], B.r[3+j],
                        A.r[i*3+2] * B.r[6+j]));
    }
    o.p[i] = fmaf(A.r[i*3+0], B.p[0],
             fmaf(A.r[i*3+1], B.p[1],
             fmaf(A.r[i*3+2], B.p[2], A.p[i])));
  }
  return o;
}

__device__ __forceinline__ Xf make_T(float phi, float st, float ct, float r) {
  float sp = __sinf(phi), cp = __cosf(phi);
  Xf T;
  T.r[0] = ct;      T.r[1] = -st;     T.r[2] = 0.f;
  T.r[3] = cp * st; T.r[4] = ct * cp; T.r[5] = -sp;
  T.r[6] = sp * st; T.r[7] = ct * sp; T.r[8] = cp;
  T.p[0] = r * ct;  T.p[1] = r * T.r[3]; T.p[2] = r * T.r[6];
  return T;
}

__device__ __forceinline__ void set_identity(Xf& X) {
  X.r[0]=1.f; X.r[1]=0.f; X.r[2]=0.f;
  X.r[3]=0.f; X.r[4]=1.f; X.r[5]=0.f;
  X.r[6]=0.f; X.r[7]=0.f; X.r[8]=1.f;
  X.p[0]=0.f; X.p[1]=0.f; X.p[2]=0.f;
}

// ---------- kernel 2: parallel rigid-transform scan ------------------------
__global__ __launch_bounds__(64) void k_scan(
    const float* __restrict__ phi, const float* __restrict__ bl,
    const float* __restrict__ ba, float* __restrict__ out) {
  const int b = blockIdx.x;       // chain 0..127
  const int t = threadIdx.x;      // lane 0..63

  float st[3], ct[3], rr[3];
#pragma unroll
  for (int j = 0; j < 3; ++j) {
    float a = ba[j];
    st[j] = __sinf(a); ct[j] = __cosf(a); rr[j] = bl[j];
  }

  float f[CHUNK];
  const float4* ph4 = (const float4*)(phi + (size_t)b * NSTEP + t * CHUNK);
#pragma unroll
  for (int q = 0; q < CHUNK/4; ++q) {
    float4 v = ph4[q];
    f[4*q+0] = v.x; f[4*q+1] = v.y; f[4*q+2] = v.z; f[4*q+3] = v.w;
  }

  Xf Q = make_T(f[0], st[0], ct[0], rr[0]);
#pragma unroll
  for (int s = 1; s < CHUNK; ++s)
    Q = compose(Q, make_T(f[s], st[s%3], ct[s%3], rr[s%3]));

#pragma unroll
  for (int d = 1; d < 64; d <<= 1) {
    Xf O;
#pragma unroll
    for (int q = 0; q < 9; ++q) O.r[q] = __shfl_up(Q.r[q], d, 64);
#pragma unroll
    for (int q = 0; q < 3; ++q) O.p[q] = __shfl_up(Q.p[q], d, 64);
    if (t < d) set_identity(O);
    Q = compose(O, Q);
  }

  Xf E;
#pragma unroll
  for (int q = 0; q < 9; ++q) E.r[q] = __shfl_up(Q.r[q], 1, 64);
#pragma unroll
  for (int q = 0; q < 3; ++q) E.p[q] = __shfl_up(Q.p[q], 1, 64);
  if (t == 0) set_identity(E);

  Xf S0;
  S0.r[0] = 0.f;                  S0.r[1] = 0.816496580927726f;   S0.r[2] = 0.5773502691896258f;
  S0.r[3] = -0.7071067811865475f; S0.r[4] = -0.4082482904638631f; S0.r[5] = 0.5773502691896258f;
  S0.r[6] = 0.7071067811865475f;  S0.r[7] = -0.4082482904638631f; S0.r[8] = 0.5773502691896258f;
  S0.p[0] = 0.f; S0.p[1] = 0.f; S0.p[2] = 1.f;

  Xf cur = compose(S0, E);

  float* op = out + (size_t)(t * CHUNK) * (BT * 3) + b * 3;
#pragma unroll
  for (int s = 0; s < CHUNK; ++s) {
    cur = compose(cur, make_T(f[s], st[s%3], ct[s%3], rr[s%3]));
    op[(size_t)s * (BT*3) + 0] = cur.p[0];
    op[(size_t)s * (BT*3) + 1] = cur.p[1];
    op[(size_t)s * (BT*3) + 2] = cur.p[2];
  }
}

// ---------- launch ---------------------------------------------------------
extern "C" void kernel_launch(void* const* d_in, const int* in_sizes, int n_in,
                              void* d_out, int out_size, void* d_ws, size_t ws_size,
                              hipStream_t stream) {
  const float* inp      = (const float*)d_in[0];
  const float* W        = (const float*)d_in[1];
  const float* bias     = (const float*)d_in[2];
  const float* alphabet = (const float*)d_in[3];
  const float* bl       = (const float*)d_in[4];
  const float* ba       = (const float*)d_in[5];
  float* out = (float*)d_out;

  float* phi = (float*)d_ws;                                    // 786432 B
  unsigned short* Wh = (unsigned short*)((char*)d_ws + 786432); // 65536 B
  unsigned short* Wl = Wh + 64 * INF;                           // 65536 B

  k_wconv<<<dim3(128), dim3(256), 0, stream>>>(W, Wh, Wl);
  k_phi<<<dim3((LSEQ*BT)/MTILE), dim3(256), 0, stream>>>(inp, Wh, Wl, bias, alphabet, phi);
  k_scan<<<dim3(BT), dim3(64), 0, stream>>>(phi, bl, ba, out);
}

// Round 9
// 221.796 us; speedup vs baseline: 1.0627x; 1.0552x over previous
//
#include <hip/hip_runtime.h>
#include <math.h>

#define LSEQ  512
#define BT    128
#define INF   512
#define HH    60
#define NSTEP 1536   // 3*LSEQ
#define CHUNK 24     // steps per lane in scan kernel: 1536 / 64

#define MTILE 128    // rows per block (k_phi); wave owns 32 rows
#define BROW  264    // LDS B row stride in bf16 (256 + 8 pad -> 2-way banks, free)

typedef __attribute__((ext_vector_type(8))) short bf16x8;
typedef __attribute__((ext_vector_type(4))) float floatx4;

// ---------- bf16 split helpers ---------------------------------------------
__device__ __forceinline__ unsigned short bf16_rn(float x) {
  unsigned u = __float_as_uint(x);
  return (unsigned short)((u + 0x7FFFu + ((u >> 16) & 1u)) >> 16);
}
__device__ __forceinline__ void split2(float x, unsigned short& h, unsigned short& l) {
  h = bf16_rn(x);
  float hf = __uint_as_float(((unsigned)h) << 16);
  l = bf16_rn(x - hf);
}

// ---------- W pre-conversion: fp32 -> (Wh, Wl) bf16 [64][512] --------------
__global__ __launch_bounds__(256) void k_wconv(
    const float* __restrict__ W, unsigned short* __restrict__ Wh,
    unsigned short* __restrict__ Wl) {
  const int idx = blockIdx.x * 256 + threadIdx.x;   // 0 .. 32767
  const int h = idx >> 9, k = idx & 511;
  float x = (h < HH) ? W[h * INF + k] : 0.f;
  unsigned short hb, lb; split2(x, hb, lb);
  Wh[idx] = hb; Wl[idx] = lb;
}

// ---------- kernel 1: split-bf16 MFMA GEMM + softmax + torsion angles ------
// B (Wh+Wl) lives in LDS, staged in two K=256 halves (64 KB each); the K-loop
// within a half is BARRIER-FREE (B is read-only), so the only global stream
// is A — fully pipelined via 1-step register prefetch. No scattered B VMEM.
// acc += Ah*Bh + Ah*Bl + Al*Bh  (split-fp32, ~2^-17 relative).
__global__ __launch_bounds__(256, 2) void k_phi(
    const float* __restrict__ inp, const unsigned short* __restrict__ Wh,
    const unsigned short* __restrict__ Wl, const float* __restrict__ bias,
    const float* __restrict__ alphabet, float* __restrict__ phi_out) {
  __shared__ unsigned short BhL[64 * BROW];   // 33792 B
  __shared__ unsigned short BlL[64 * BROW];   // 33792 B
  __shared__ float sS[HH * 3], sC[HH * 3], sBias[64];

  const int tid  = threadIdx.x;
  const int lane = tid & 63;
  const int wid  = tid >> 6;
  const int c    = lane & 15;        // frag row/col index
  const int quad = lane >> 4;        // 0..3
  const int row0 = blockIdx.x * MTILE;

  if (tid < HH * 3) { float a = alphabet[tid]; sS[tid] = __sinf(a); sC[tid] = __cosf(a); }
  if (tid >= 192 && tid < 256) { int n = tid - 192; sBias[n] = (n < HH) ? bias[n] : 0.f; }

  floatx4 acc[2][4];
#pragma unroll
  for (int mt = 0; mt < 2; ++mt)
#pragma unroll
    for (int nt = 0; nt < 4; ++nt) acc[mt][nt] = (floatx4){0.f, 0.f, 0.f, 0.f};

  // per-lane A row bases (m-tile mt row = wid*32 + 16*mt + c), k-offset quad*8
  const float* ap0 = inp + (size_t)(row0 + wid * 32 + c)      * INF + quad * 8;
  const float* ap1 = ap0 + 16 * INF;

  for (int half = 0; half < 2; ++half) {
    const int kbase = half * 256;
    if (half) __syncthreads();          // all waves done reading previous half
    // ---- stage B half: 64 x 256 of Wh and Wl -> LDS (coalesced uint4) ----
#pragma unroll
    for (int i = 0; i < 8; ++i) {
      const int chunk = i * 256 + tid;  // 0..2047 ; 32 chunks of 8 bf16 per row
      const int r = chunk >> 5;
      const int j = (chunk & 31) * 8;
      *(uint4*)&BhL[r * BROW + j] = *(const uint4*)(Wh + (size_t)r * INF + kbase + j);
      *(uint4*)&BlL[r * BROW + j] = *(const uint4*)(Wl + (size_t)r * INF + kbase + j);
    }
    __syncthreads();

    // ---- prefetch A for step 0 of this half ----
    float4 pa0, pa1, pa2, pa3;
    pa0 = *(const float4*)(ap0 + kbase);
    pa1 = *(const float4*)(ap0 + kbase + 4);
    pa2 = *(const float4*)(ap1 + kbase);
    pa3 = *(const float4*)(ap1 + kbase + 4);

#pragma unroll
    for (int ks = 0; ks < 8; ++ks) {    // K=32 per step, barrier-free
      const int kl = ks * 32;           // k within half
      float4 a00 = pa0, a01 = pa1, a10 = pa2, a11 = pa3;
      if (ks + 1 < 8) {                 // issue next step's A loads now
        pa0 = *(const float4*)(ap0 + kbase + kl + 32);
        pa1 = *(const float4*)(ap0 + kbase + kl + 36);
        pa2 = *(const float4*)(ap1 + kbase + kl + 32);
        pa3 = *(const float4*)(ap1 + kbase + kl + 36);
      }
      // ---- B fragments from LDS (2-way banks = free) ----
      bf16x8 Bh[4], Bl[4];
#pragma unroll
      for (int nt = 0; nt < 4; ++nt) {
        const int boff = (nt * 16 + c) * BROW + kl + quad * 8;
        Bh[nt] = *(const bf16x8*)&BhL[boff];
        Bl[nt] = *(const bf16x8*)&BlL[boff];
      }
      // ---- split A to bf16 h/l fragments in registers ----
      bf16x8 Ah[2], Al[2];
      {
        float av[2][8] = {{a00.x,a00.y,a00.z,a00.w,a01.x,a01.y,a01.z,a01.w},
                          {a10.x,a10.y,a10.z,a10.w,a11.x,a11.y,a11.z,a11.w}};
#pragma unroll
        for (int mt = 0; mt < 2; ++mt)
#pragma unroll
          for (int j = 0; j < 8; ++j) {
            unsigned short hb, lb; split2(av[mt][j], hb, lb);
            Ah[mt][j] = (short)hb; Al[mt][j] = (short)lb;
          }
      }
#pragma unroll
      for (int mt = 0; mt < 2; ++mt)
#pragma unroll
        for (int nt = 0; nt < 4; ++nt) {
          acc[mt][nt] = __builtin_amdgcn_mfma_f32_16x16x32_bf16(Ah[mt], Bh[nt], acc[mt][nt], 0, 0, 0);
          acc[mt][nt] = __builtin_amdgcn_mfma_f32_16x16x32_bf16(Ah[mt], Bl[nt], acc[mt][nt], 0, 0, 0);
          acc[mt][nt] = __builtin_amdgcn_mfma_f32_16x16x32_bf16(Al[mt], Bh[nt], acc[mt][nt], 0, 0, 0);
        }
    }
  }

  // ---- epilogue: C/D layout row = quad*4+reg, col = lane&15 ----
#pragma unroll
  for (int mt = 0; mt < 2; ++mt) {
#pragma unroll
    for (int reg = 0; reg < 4; ++reg) {
      float lg[4];  bool val[4];
#pragma unroll
      for (int nt = 0; nt < 4; ++nt) {
        const int n = nt * 16 + c;
        val[nt] = (n < HH);
        lg[nt] = acc[mt][nt][reg] + sBias[n];
      }
      float m = -1e30f;
#pragma unroll
      for (int nt = 0; nt < 4; ++nt) if (val[nt]) m = fmaxf(m, lg[nt]);
#pragma unroll
      for (int d = 1; d < 16; d <<= 1) m = fmaxf(m, __shfl_xor(m, d, 64));

      float s0=0.f,c0=0.f,s1=0.f,c1=0.f,s2=0.f,c2=0.f;
#pragma unroll
      for (int nt = 0; nt < 4; ++nt) {
        const int n = nt * 16 + c;
        float e = val[nt] ? __expf(lg[nt] - m) : 0.f;
        s0 = fmaf(e, sS[n*3+0], s0);  c0 = fmaf(e, sC[n*3+0], c0);
        s1 = fmaf(e, sS[n*3+1], s1);  c1 = fmaf(e, sC[n*3+1], c1);
        s2 = fmaf(e, sS[n*3+2], s2);  c2 = fmaf(e, sC[n*3+2], c2);
      }
#pragma unroll
      for (int d = 1; d < 16; d <<= 1) {
        s0 += __shfl_xor(s0, d, 64);  c0 += __shfl_xor(c0, d, 64);
        s1 += __shfl_xor(s1, d, 64);  c1 += __shfl_xor(c1, d, 64);
        s2 += __shfl_xor(s2, d, 64);  c2 += __shfl_xor(c2, d, 64);
      }
      if (c == 0) {
        const int row = row0 + wid * 32 + mt * 16 + quad * 4 + reg;
        const int l  = row >> 7;        // / BT
        const int bb = row & 127;       // % BT
        float* pp = phi_out + (size_t)bb * NSTEP + 3 * l;
        pp[0] = atan2f(s0, c0);
        pp[1] = atan2f(s1, c1);
        pp[2] = atan2f(s2, c2);
      }
    }
  }
}

// ---------- rigid transform (3x3 rotation row-major + translation) ----------
struct Xf { float r[9]; float p[3]; };

__device__ __forceinline__ Xf compose(const Xf& A, const Xf& B) {
  Xf o;
#pragma unroll
  for (int i = 0; i < 3; ++i) {
#pragma unroll
    for (int j = 0; j < 3; ++j) {
      o.r[i*3+j] = fmaf(A.r[i*3+0], B.r[0+j],
                   fmaf(A.r[i*3+1], B.r[3+j],
                        A.r[i*3+2] * B.r[6+j]));
    }
    o.p[i] = fmaf(A.r[i*3+0], B.p[0],
             fmaf(A.r[i*3+1], B.p[1],
             fmaf(A.r[i*3+2], B.p[2], A.p[i])));
  }
  return o;
}

__device__ __forceinline__ Xf make_T(float phi, float st, float ct, float r) {
  float sp = __sinf(phi), cp = __cosf(phi);
  Xf T;
  T.r[0] = ct;      T.r[1] = -st;     T.r[2] = 0.f;
  T.r[3] = cp * st; T.r[4] = ct * cp; T.r[5] = -sp;
  T.r[6] = sp * st; T.r[7] = ct * sp; T.r[8] = cp;
  T.p[0] = r * ct;  T.p[1] = r * T.r[3]; T.p[2] = r * T.r[6];
  return T;
}

__device__ __forceinline__ void set_identity(Xf& X) {
  X.r[0]=1.f; X.r[1]=0.f; X.r[2]=0.f;
  X.r[3]=0.f; X.r[4]=1.f; X.r[5]=0.f;
  X.r[6]=0.f; X.r[7]=0.f; X.r[8]=1.f;
  X.p[0]=0.f; X.p[1]=0.f; X.p[2]=0.f;
}

// ---------- kernel 2: parallel rigid-transform scan ------------------------
__global__ __launch_bounds__(64) void k_scan(
    const float* __restrict__ phi, const float* __restrict__ bl,
    const float* __restrict__ ba, float* __restrict__ out) {
  const int b = blockIdx.x;       // chain 0..127
  const int t = threadIdx.x;      // lane 0..63

  float st[3], ct[3], rr[3];
#pragma unroll
  for (int j = 0; j < 3; ++j) {
    float a = ba[j];
    st[j] = __sinf(a); ct[j] = __cosf(a); rr[j] = bl[j];
  }

  float f[CHUNK];
  const float4* ph4 = (const float4*)(phi + (size_t)b * NSTEP + t * CHUNK);
#pragma unroll
  for (int q = 0; q < CHUNK/4; ++q) {
    float4 v = ph4[q];
    f[4*q+0] = v.x; f[4*q+1] = v.y; f[4*q+2] = v.z; f[4*q+3] = v.w;
  }

  Xf Q = make_T(f[0], st[0], ct[0], rr[0]);
#pragma unroll
  for (int s = 1; s < CHUNK; ++s)
    Q = compose(Q, make_T(f[s], st[s%3], ct[s%3], rr[s%3]));

#pragma unroll
  for (int d = 1; d < 64; d <<= 1) {
    Xf O;
#pragma unroll
    for (int q = 0; q < 9; ++q) O.r[q] = __shfl_up(Q.r[q], d, 64);
#pragma unroll
    for (int q = 0; q < 3; ++q) O.p[q] = __shfl_up(Q.p[q], d, 64);
    if (t < d) set_identity(O);
    Q = compose(O, Q);
  }

  Xf E;
#pragma unroll
  for (int q = 0; q < 9; ++q) E.r[q] = __shfl_up(Q.r[q], 1, 64);
#pragma unroll
  for (int q = 0; q < 3; ++q) E.p[q] = __shfl_up(Q.p[q], 1, 64);
  if (t == 0) set_identity(E);

  Xf S0;
  S0.r[0] = 0.f;                  S0.r[1] = 0.816496580927726f;   S0.r[2] = 0.5773502691896258f;
  S0.r[3] = -0.7071067811865475f; S0.r[4] = -0.4082482904638631f; S0.r[5] = 0.5773502691896258f;
  S0.r[6] = 0.7071067811865475f;  S0.r[7] = -0.4082482904638631f; S0.r[8] = 0.5773502691896258f;
  S0.p[0] = 0.f; S0.p[1] = 0.f; S0.p[2] = 1.f;

  Xf cur = compose(S0, E);

  float* op = out + (size_t)(t * CHUNK) * (BT * 3) + b * 3;
#pragma unroll
  for (int s = 0; s < CHUNK; ++s) {
    cur = compose(cur, make_T(f[s], st[s%3], ct[s%3], rr[s%3]));
    op[(size_t)s * (BT*3) + 0] = cur.p[0];
    op[(size_t)s * (BT*3) + 1] = cur.p[1];
    op[(size_t)s * (BT*3) + 2] = cur.p[2];
  }
}

// ---------- launch ---------------------------------------------------------
extern "C" void kernel_launch(void* const* d_in, const int* in_sizes, int n_in,
                              void* d_out, int out_size, void* d_ws, size_t ws_size,
                              hipStream_t stream) {
  const float* inp      = (const float*)d_in[0];
  const float* W        = (const float*)d_in[1];
  const float* bias     = (const float*)d_in[2];
  const float* alphabet = (const float*)d_in[3];
  const float* bl       = (const float*)d_in[4];
  const float* ba       = (const float*)d_in[5];
  float* out = (float*)d_out;

  float* phi = (float*)d_ws;                                    // 786432 B
  unsigned short* Wh = (unsigned short*)((char*)d_ws + 786432); // 65536 B
  unsigned short* Wl = Wh + 64 * INF;                           // 65536 B

  k_wconv<<<dim3(128), dim3(256), 0, stream>>>(W, Wh, Wl);
  k_phi<<<dim3((LSEQ*BT)/MTILE), dim3(256), 0, stream>>>(inp, Wh, Wl, bias, alphabet, phi);
  k_scan<<<dim3(BT), dim3(64), 0, stream>>>(phi, bl, ba, out);
}